// Round 1
// baseline (328.079 us; speedup 1.0000x reference)
//
#include <hip/hip_runtime.h>
#include <stdint.h>

// CustomLSTMCell: B=4096, I=512, H=1024, fp32 in/out.
// Strategy: cast hx/W to bf16 (fp32 accumulate via MFMA), fuse both branches'
// 8 gate-GEMMs + epilogue in one kernel. c_temp (d_in[4]) is dead in the ref.
//
// ws layout (bf16, 48 MB total; requires ws_size >= 50,331,648 B):
//   wsA: [2][4096][1536]  hx per branch = [h_branch | y], pre-swizzled
//   wsW: [8][1024][1536]  weights (light f,i,c,o then temp f,i,c,o), pre-swizzled
// Pre-swizzle: within each row's 8x16B-chunk group (BK=64), chunk c is stored at
// c ^ (row&7). global_load_lds stages linearly (it cannot scatter), ds_read
// applies the same XOR -> conflict-free ds_read_b128 (T2, rule #21).

#define B_DIM 4096
#define I_DIM 512
#define H_DIM 1024
#define K_DIM 1536

typedef __attribute__((ext_vector_type(8))) __bf16 bf16x8;
typedef __attribute__((ext_vector_type(4))) float f32x4;
typedef __attribute__((ext_vector_type(4))) uint32_t u32x4;

static __device__ __forceinline__ uint32_t f2bf(float f) {
  uint32_t u = __builtin_bit_cast(uint32_t, f);
  return (u + 0x7FFFu + ((u >> 16) & 1u)) >> 16;  // RNE, NaN ignored (inputs finite)
}
static __device__ __forceinline__ uint32_t pack2(float lo, float hi) {
  return f2bf(lo) | (f2bf(hi) << 16);
}
static __device__ __forceinline__ float sigf(float x) {
  return 1.f / (1.f + __expf(-x));
}
static __device__ __forceinline__ float tanhfast(float x) {
  float t = __expf(fminf(2.f * x, 80.f));   // clamp: no inf/inf
  return (t - 1.f) / (t + 1.f);
}

// ---------------- conversion: fp32 -> bf16, pre-swizzled ----------------
__global__ __launch_bounds__(256) void convert_kernel(
    const float* __restrict__ y, const float* __restrict__ h_light,
    const float* __restrict__ h_temp,
    const float* __restrict__ w0, const float* __restrict__ w1,
    const float* __restrict__ w2, const float* __restrict__ w3,
    const float* __restrict__ w4, const float* __restrict__ w5,
    const float* __restrict__ w6, const float* __restrict__ w7,
    uint16_t* __restrict__ ws)
{
  const int CPR = K_DIM / 8;                  // 192 16B-chunks per row
  const int A_CHUNKS = 2 * B_DIM * CPR;       // 1,572,864
  const int TOT = A_CHUNKS + 8 * H_DIM * CPR; // 3,145,728
  for (int chunk = blockIdx.x * 256 + threadIdx.x; chunk < TOT;
       chunk += gridDim.x * 256) {
    int row_all = chunk / CPR;
    int cs = chunk - row_all * CPR;           // stored chunk within row
    int cl = (cs & ~7) | ((cs & 7) ^ (row_all & 7));  // logical chunk
    int k0 = cl * 8;
    const float* src;
    if (chunk < A_CHUNKS) {
      int branch = row_all >> 12;
      int row = row_all & (B_DIM - 1);
      const float* hb = branch ? h_temp : h_light;
      src = (k0 < H_DIM) ? (hb + (size_t)row * H_DIM + k0)
                         : (y + (size_t)row * I_DIM + (k0 - H_DIM));
    } else {
      int ra = row_all - 2 * B_DIM;
      int mat = ra >> 10;
      int row = ra & (H_DIM - 1);
      const float* w = (mat < 4) ? ((mat < 2) ? (mat == 0 ? w0 : w1) : (mat == 2 ? w2 : w3))
                                 : ((mat < 6) ? (mat == 4 ? w4 : w5) : (mat == 6 ? w6 : w7));
      src = w + (size_t)row * K_DIM + k0;
    }
    f32x4 v0 = *(const f32x4*)src;
    f32x4 v1 = *(const f32x4*)(src + 4);
    u32x4 o;
    o[0] = pack2(v0[0], v0[1]);
    o[1] = pack2(v0[2], v0[3]);
    o[2] = pack2(v1[0], v1[1]);
    o[3] = pack2(v1[2], v1[3]);
    *(u32x4*)(ws + (size_t)chunk * 8) = o;
  }
}

// ---------------- fused 8-matrix GEMM + LSTM epilogue ----------------
// Grid 512 blocks (32 bm x 16 bn), 512 threads = 8 waves.
// Wave w computes z for matrix w (0-3: light f,i,c,o; 4-7: temp f,i,c,o)
// over the whole [128 x 64] tile: acc[8][4] fragments of 16x16.
__global__ __launch_bounds__(512, 2) void lstm_fused_kernel(
    const uint16_t* __restrict__ ws,
    const float* __restrict__ c_light,
    const float* __restrict__ bf1, const float* __restrict__ bi1,
    const float* __restrict__ bc1, const float* __restrict__ bo1,
    const float* __restrict__ bf2, const float* __restrict__ bi2,
    const float* __restrict__ bc2, const float* __restrict__ bo2,
    float* __restrict__ out)
{
  __shared__ alignas(128) char smem[96 * 1024];
  // staging: A_l[128][64]bf16 @0 (16KB), A_t @16KB, B[w][64][64]bf16 @32KB+w*8KB
  // epilogue reuse: z[8][32][68] f32 (69.6KB)

  const int tid = threadIdx.x;
  const int lane = tid & 63;
  const int wv = tid >> 6;

  // XCD-aware bijective swizzle (512 % 8 == 0)
  int bid = blockIdx.x;
  int wg = (bid & 7) * 64 + (bid >> 3);
  const int bm0 = (wg >> 4) * 128;
  const int bn0 = (wg & 15) * 64;

  const uint16_t* wsA = ws;
  const uint16_t* wsW = ws + (size_t)2 * B_DIM * K_DIM;

  const int rA = lane & 15;   // row-within-16 for A/B fragments
  const int kg = lane >> 4;   // k-chunk group 0..3
  const int swz = rA & 7;
  const int branch = wv >> 2;
  const char* As = smem + branch * 16384;
  const char* Bs = smem + 32768 + wv * 8192;

  f32x4 acc[8][4];
#pragma unroll
  for (int m = 0; m < 8; ++m)
#pragma unroll
    for (int n = 0; n < 4; ++n) acc[m][n] = (f32x4){0.f, 0.f, 0.f, 0.f};

  for (int kt = 0; kt < K_DIM / 64; ++kt) {
    __syncthreads();  // previous iteration's ds_reads done before overwrite
#pragma unroll
    for (int i = 0; i < 12; ++i) {
      int chunk = i * 512 + tid;  // LDS dest = wave-uniform base + lane*16
      const uint16_t* src;
      if (chunk < 2048) {         // A: 2 x 128 rows x 8 chunks
        int br = chunk >> 10;
        int r = (chunk >> 3) & 127;
        int c = chunk & 7;
        src = wsA + (size_t)br * (B_DIM * K_DIM) + (size_t)(bm0 + r) * K_DIM + kt * 64 + c * 8;
      } else {                    // B: 8 mats x 64 rows x 8 chunks
        int cb2 = chunk - 2048;
        int mt = cb2 >> 9;
        int r = (cb2 >> 3) & 63;
        int c = cb2 & 7;
        src = wsW + (size_t)mt * (H_DIM * K_DIM) + (size_t)(bn0 + r) * K_DIM + kt * 64 + c * 8;
      }
      __builtin_amdgcn_global_load_lds(
          (const __attribute__((address_space(1))) void*)src,
          (__attribute__((address_space(3))) void*)(smem + chunk * 16),
          16, 0, 0);
    }
    asm volatile("s_waitcnt vmcnt(0)" ::: "memory");
    __syncthreads();

#pragma unroll
    for (int kk = 0; kk < 2; ++kk) {
      const int cs = (kk * 4 + kg) ^ swz;   // swizzled chunk to read
      bf16x8 a[8];
      bf16x8 b[4];
#pragma unroll
      for (int m = 0; m < 8; ++m)
        a[m] = *(const bf16x8*)(As + (m * 16 + rA) * 128 + cs * 16);
#pragma unroll
      for (int n = 0; n < 4; ++n)
        b[n] = *(const bf16x8*)(Bs + (n * 16 + rA) * 128 + cs * 16);
#pragma unroll
      for (int m = 0; m < 8; ++m)
#pragma unroll
        for (int n = 0; n < 4; ++n)
          acc[m][n] = __builtin_amdgcn_mfma_f32_16x16x32_bf16(a[m], b[n], acc[m][n], 0, 0, 0);
    }
  }

  // ---- epilogue: 4 chunks of 32 rows through LDS ----
  float* zst = (float*)smem;  // [8][32][68] f32, +4 pad kills write conflicts
#pragma unroll
  for (int q = 0; q < 4; ++q) {
    __syncthreads();
#pragma unroll
    for (int mm = 0; mm < 2; ++mm)
#pragma unroll
      for (int n = 0; n < 4; ++n)
#pragma unroll
        for (int j = 0; j < 4; ++j) {
          int r = mm * 16 + kg * 4 + j;     // C/D layout: row=(l>>4)*4+j, col=l&15
          int c = n * 16 + rA;
          zst[wv * 2176 + r * 68 + c] = acc[q * 2 + mm][n][j];
        }
    __syncthreads();

    int r = tid >> 4;           // 0..31
    int cb = (tid & 15) * 4;    // 0..60
    int grow = bm0 + q * 32 + r;
    int gc = bn0 + cb;
    const float* zb = zst + r * 68 + cb;
    f32x4 z0 = *(const f32x4*)(zb + 0 * 2176) + *(const f32x4*)(bf1 + gc);
    f32x4 z1 = *(const f32x4*)(zb + 1 * 2176) + *(const f32x4*)(bi1 + gc);
    f32x4 z2 = *(const f32x4*)(zb + 2 * 2176) + *(const f32x4*)(bc1 + gc);
    f32x4 z3 = *(const f32x4*)(zb + 3 * 2176) + *(const f32x4*)(bo1 + gc);
    f32x4 z4 = *(const f32x4*)(zb + 4 * 2176) + *(const f32x4*)(bf2 + gc);
    f32x4 z5 = *(const f32x4*)(zb + 5 * 2176) + *(const f32x4*)(bi2 + gc);
    f32x4 z6 = *(const f32x4*)(zb + 6 * 2176) + *(const f32x4*)(bc2 + gc);
    f32x4 z7 = *(const f32x4*)(zb + 7 * 2176) + *(const f32x4*)(bo2 + gc);
    f32x4 cl4 = *(const f32x4*)(c_light + (size_t)grow * H_DIM + gc);
    f32x4 hv, cv;
#pragma unroll
    for (int j = 0; j < 4; ++j) {
      float f1 = sigf(z0[j]);
      float i1 = sigf(z1[j]);
      float ch1 = tanhfast(z2[j]);
      float o1 = sigf(z3[j]);
      float f2 = sigf(z4[j]);
      float i2 = sigf(z5[j]);
      float ch2 = tanhfast(z6[j]);
      float o2 = sigf(z7[j]);
      float cn = f1 * cl4[j] + i1 * ch1 + f2 * cl4[j] + i2 * ch2;
      hv[j] = (o1 + o2) * tanhfast(cn);
      cv[j] = cn;
    }
    *(f32x4*)(out + (size_t)grow * H_DIM + gc) = hv;
    *(f32x4*)(out + (size_t)(B_DIM * H_DIM) + (size_t)grow * H_DIM + gc) = cv;
  }
}

extern "C" void kernel_launch(void* const* d_in, const int* in_sizes, int n_in,
                              void* d_out, int out_size, void* d_ws, size_t ws_size,
                              hipStream_t stream) {
  (void)in_sizes; (void)n_in; (void)out_size; (void)ws_size;
  const float* y       = (const float*)d_in[0];
  const float* h_light = (const float*)d_in[1];
  const float* c_light = (const float*)d_in[2];
  const float* h_temp  = (const float*)d_in[3];
  // d_in[4] = c_temp: dead in the reference computation.
  uint16_t* ws = (uint16_t*)d_ws;  // needs 50,331,648 B

  convert_kernel<<<2048, 256, 0, stream>>>(
      y, h_light, h_temp,
      (const float*)d_in[5],  (const float*)d_in[7],  (const float*)d_in[9],  (const float*)d_in[11],
      (const float*)d_in[13], (const float*)d_in[15], (const float*)d_in[17], (const float*)d_in[19],
      ws);

  lstm_fused_kernel<<<512, 512, 0, stream>>>(
      ws, c_light,
      (const float*)d_in[6],  (const float*)d_in[8],  (const float*)d_in[10], (const float*)d_in[12],
      (const float*)d_in[14], (const float*)d_in[16], (const float*)d_in[18], (const float*)d_in[20],
      (float*)d_out);
}

// Round 3
// 303.127 us; speedup vs baseline: 1.0823x; 1.0823x over previous
//
#include <hip/hip_runtime.h>
#include <stdint.h>

// CustomLSTMCell: B=4096, I=512, H=1024, fp32 in/out.
// R2 (resubmit — R2 bench failed on GPU acquisition, kernel unmeasured):
// counted-vmcnt 3-buffer pipeline (T3+T4), BK=32, 2x16-MFMA phases/K-step,
// T5 setprio, T2 swizzle ((row>>1)&3 over 4-chunk groups).
// c_temp (d_in[4]) is dead in the reference.
//
// ws layout (bf16, 48 MB): wsA [2][4096][1536] hx rows, wsW [8][1024][1536],
// both pre-swizzled: within each 4-chunk (64B) group, chunk c stored at
// c ^ ((row>>1)&3). global_load_lds stages linearly; ds_read applies the
// same XOR -> every 8 consecutive lanes of ds_read_b128 hit all 32 banks once.

#define B_DIM 4096
#define I_DIM 512
#define H_DIM 1024
#define K_DIM 1536
#define NK 48              // K-steps of 32
#define BUFB (48 * 1024)   // LDS bytes per pipeline buffer

typedef __attribute__((ext_vector_type(8))) __bf16 bf16x8;
typedef __attribute__((ext_vector_type(4))) float f32x4;
typedef __attribute__((ext_vector_type(4))) uint32_t u32x4;

static __device__ __forceinline__ uint32_t f2bf(float f) {
  uint32_t u = __builtin_bit_cast(uint32_t, f);
  return (u + 0x7FFFu + ((u >> 16) & 1u)) >> 16;  // RNE (inputs finite)
}
static __device__ __forceinline__ uint32_t pack2(float lo, float hi) {
  return f2bf(lo) | (f2bf(hi) << 16);
}
static __device__ __forceinline__ float sigf(float x) {
  return 1.f / (1.f + __expf(-x));
}
static __device__ __forceinline__ float tanhfast(float x) {
  float t = __expf(fminf(2.f * x, 80.f));
  return (t - 1.f) / (t + 1.f);
}

// ---------------- conversion: fp32 -> bf16, pre-swizzled ----------------
// One 16B chunk per thread: row = blockIdx.x (16384 rows), cs = threadIdx.x.
__global__ __launch_bounds__(192) void convert_kernel(
    const float* __restrict__ y, const float* __restrict__ h_light,
    const float* __restrict__ h_temp,
    const float* __restrict__ w0, const float* __restrict__ w1,
    const float* __restrict__ w2, const float* __restrict__ w3,
    const float* __restrict__ w4, const float* __restrict__ w5,
    const float* __restrict__ w6, const float* __restrict__ w7,
    uint16_t* __restrict__ ws)
{
  const int row_all = blockIdx.x;     // 0..16383: [2][4096] A rows then [8][1024] W rows
  const int cs = threadIdx.x;         // stored chunk 0..191
  const int cl = (cs & ~3) | ((cs & 3) ^ ((row_all >> 1) & 3));  // logical chunk
  const int k0 = cl * 8;
  const float* src;
  if (row_all < 2 * B_DIM) {
    const int branch = row_all >> 12;
    const int row = row_all & (B_DIM - 1);
    const float* hb = branch ? h_temp : h_light;
    src = (k0 < H_DIM) ? (hb + (size_t)row * H_DIM + k0)
                       : (y + (size_t)row * I_DIM + (k0 - H_DIM));
  } else {
    const int ra = row_all - 2 * B_DIM;
    const int mat = ra >> 10;
    const int row = ra & (H_DIM - 1);
    const float* w = (mat < 4) ? ((mat < 2) ? (mat == 0 ? w0 : w1) : (mat == 2 ? w2 : w3))
                               : ((mat < 6) ? (mat == 4 ? w4 : w5) : (mat == 6 ? w6 : w7));
    src = w + (size_t)row * K_DIM + k0;
  }
  f32x4 v0 = *(const f32x4*)src;
  f32x4 v1 = *(const f32x4*)(src + 4);
  u32x4 o;
  o[0] = pack2(v0[0], v0[1]);
  o[1] = pack2(v0[2], v0[3]);
  o[2] = pack2(v1[0], v1[1]);
  o[3] = pack2(v1[2], v1[3]);
  *(u32x4*)(ws + ((size_t)row_all * 192 + cs) * 8) = o;
}

// ---------------- fused 8-matrix GEMM + LSTM epilogue ----------------
// Grid 512 blocks (32 bm x 16 bn), 512 threads = 8 waves; wave w owns mat w.
// 3-deep LDS pipeline: compute buf[t%3] while loads for t+2 fly; vmcnt(6).
__global__ __launch_bounds__(512, 2) void lstm_fused_kernel(
    const uint16_t* __restrict__ ws,
    const float* __restrict__ c_light,
    const float* __restrict__ bf1, const float* __restrict__ bi1,
    const float* __restrict__ bc1, const float* __restrict__ bo1,
    const float* __restrict__ bf2, const float* __restrict__ bi2,
    const float* __restrict__ bc2, const float* __restrict__ bo2,
    float* __restrict__ out)
{
  __shared__ alignas(128) char smem[3 * BUFB];  // 144 KB; epilogue reuses it

  const int tid = threadIdx.x;
  const int lane = tid & 63;
  const int wv = tid >> 6;

  // XCD-aware bijective swizzle (512 % 8 == 0)
  const int bid = blockIdx.x;
  const int wg = (bid & 7) * 64 + (bid >> 3);
  const int bm0 = (wg >> 4) * 128;
  const int bn0 = (wg & 15) * 64;

  const uint16_t* wsA = ws;
  const uint16_t* wsW = ws + (size_t)2 * B_DIM * K_DIM;

  const int rA = lane & 15;
  const int kg = lane >> 4;
  // frag byte offset within a [rows][4-chunk] pane (row stride 64B), T2-swizzled
  const uint32_t fo = (uint32_t)rA * 64u + (uint32_t)((kg ^ ((rA >> 1) & 3))) * 16u;

  // per-thread staging sources; chunk c of buffer: c<1024 A [2][128][4], else B [8][64][4]
  const uint16_t* sA0;
  const uint16_t* sA1;
  const uint16_t* sB[4];
  {
    int c = tid;  // branch 0
    sA0 = wsA + (size_t)(bm0 + ((c >> 2) & 127)) * K_DIM + (c & 3) * 8;
    c = 512 + tid;  // branch 1
    sA1 = wsA + (size_t)B_DIM * K_DIM + (size_t)(bm0 + ((c >> 2) & 127)) * K_DIM + (c & 3) * 8;
#pragma unroll
    for (int j = 0; j < 4; ++j) {
      int c2 = j * 512 + tid;
      sB[j] = wsW + (size_t)(c2 >> 8) * ((size_t)H_DIM * K_DIM) +
              (size_t)(bn0 + ((c2 >> 2) & 63)) * K_DIM + (c2 & 3) * 8;
    }
  }
  const uint32_t ldA0 = (uint32_t)tid * 16u;
  const uint32_t ldA1 = (uint32_t)(512 + tid) * 16u;
  uint32_t ldB[4];
#pragma unroll
  for (int j = 0; j < 4; ++j) ldB[j] = (uint32_t)(1024 + j * 512 + tid) * 16u;

  const uint32_t aBase = (uint32_t)(wv >> 2) * 8192u;           // branch pane
  const uint32_t bBase = 16384u + (uint32_t)wv * 4096u;         // mat pane

#define ISSUE(srcp, ldsoff, tg)                                              \
  __builtin_amdgcn_global_load_lds(                                          \
      (const __attribute__((address_space(1))) void*)(srcp),                 \
      (__attribute__((address_space(3))) void*)(&smem[(size_t)(tg)*BUFB + (ldsoff)]), \
      16, 0, 0)

  f32x4 acc[8][4];
#pragma unroll
  for (int m = 0; m < 8; ++m)
#pragma unroll
    for (int n = 0; n < 4; ++n) acc[m][n] = (f32x4){0.f, 0.f, 0.f, 0.f};

  // ---- prologue: stage K-steps 0 and 1 ----
  ISSUE(sA0, ldA0, 0); ISSUE(sA1, ldA1, 0);
#pragma unroll
  for (int j = 0; j < 4; ++j) ISSUE(sB[j], ldB[j], 0);
  ISSUE(sA0 + 32, ldA0, 1); ISSUE(sA1 + 32, ldA1, 1);
#pragma unroll
  for (int j = 0; j < 4; ++j) ISSUE(sB[j] + 32, ldB[j], 1);
  sA0 += 64; sA1 += 64;
#pragma unroll
  for (int j = 0; j < 4; ++j) sB[j] += 64;
  asm volatile("s_waitcnt vmcnt(6)" ::: "memory");  // buf0 landed (buf1 may fly)
  __builtin_amdgcn_s_barrier();

  for (int kt = 0; kt < NK; ++kt) {
    const int bi = kt % 3;
    const int tg = (bi == 0) ? 2 : bi - 1;  // (kt+2)%3
    const char* As = smem + (size_t)bi * BUFB + aBase;
    const char* Bs = smem + (size_t)bi * BUFB + bBase;
    const bool pf = (kt + 2 < NK);

    // ---- phase 1: m=0..3 ----
    bf16x8 Af[4], Bf[4];
#pragma unroll
    for (int m = 0; m < 4; ++m) Af[m] = *(const bf16x8*)(As + m * 1024 + fo);
#pragma unroll
    for (int n = 0; n < 4; ++n) Bf[n] = *(const bf16x8*)(Bs + n * 1024 + fo);
    if (pf) { ISSUE(sA0, ldA0, tg); ISSUE(sA1, ldA1, tg); ISSUE(sB[0], ldB[0], tg); }
    __builtin_amdgcn_s_barrier();
    asm volatile("s_waitcnt lgkmcnt(0)" ::: "memory");
    __builtin_amdgcn_s_setprio(1);
#pragma unroll
    for (int m = 0; m < 4; ++m)
#pragma unroll
      for (int n = 0; n < 4; ++n)
        acc[m][n] = __builtin_amdgcn_mfma_f32_16x16x32_bf16(Af[m], Bf[n], acc[m][n], 0, 0, 0);
    __builtin_amdgcn_s_setprio(0);
    __builtin_amdgcn_s_barrier();

    // ---- phase 2: m=4..7 (B frags reused from registers) ----
    bf16x8 Ag[4];
#pragma unroll
    for (int m = 0; m < 4; ++m) Ag[m] = *(const bf16x8*)(As + (m + 4) * 1024 + fo);
    if (pf) { ISSUE(sB[1], ldB[1], tg); ISSUE(sB[2], ldB[2], tg); ISSUE(sB[3], ldB[3], tg); }
    __builtin_amdgcn_s_barrier();
    asm volatile("s_waitcnt lgkmcnt(0)" ::: "memory");
    __builtin_amdgcn_s_setprio(1);
#pragma unroll
    for (int m = 0; m < 4; ++m)
#pragma unroll
      for (int n = 0; n < 4; ++n)
        acc[m + 4][n] = __builtin_amdgcn_mfma_f32_16x16x32_bf16(Ag[m], Bf[n], acc[m + 4][n], 0, 0, 0);
    __builtin_amdgcn_s_setprio(0);
    // counted wait for the buffer the NEXT iteration reads — never 0 mid-loop
    if (kt + 2 < NK) asm volatile("s_waitcnt vmcnt(6)" ::: "memory");
    else             asm volatile("s_waitcnt vmcnt(0)" ::: "memory");
    __builtin_amdgcn_s_barrier();

    sA0 += 32; sA1 += 32;
#pragma unroll
    for (int j = 0; j < 4; ++j) sB[j] += 32;
  }
#undef ISSUE

  // ---- epilogue: 4 chunks of 32 rows through LDS ----
  float* zst = (float*)smem;  // [8][32][68] f32
#pragma unroll
  for (int q = 0; q < 4; ++q) {
    __syncthreads();
#pragma unroll
    for (int mm = 0; mm < 2; ++mm)
#pragma unroll
      for (int n = 0; n < 4; ++n)
#pragma unroll
        for (int j = 0; j < 4; ++j) {
          int r = mm * 16 + kg * 4 + j;  // C/D: row=(l>>4)*4+j, col=l&15
          int c = n * 16 + rA;
          zst[wv * 2176 + r * 68 + c] = acc[q * 2 + mm][n][j];
        }
    __syncthreads();

    int r = tid >> 4;
    int cb = (tid & 15) * 4;
    int grow = bm0 + q * 32 + r;
    int gc = bn0 + cb;
    const float* zb = zst + r * 68 + cb;
    f32x4 z0 = *(const f32x4*)(zb + 0 * 2176) + *(const f32x4*)(bf1 + gc);
    f32x4 z1 = *(const f32x4*)(zb + 1 * 2176) + *(const f32x4*)(bi1 + gc);
    f32x4 z2 = *(const f32x4*)(zb + 2 * 2176) + *(const f32x4*)(bc1 + gc);
    f32x4 z3 = *(const f32x4*)(zb + 3 * 2176) + *(const f32x4*)(bo1 + gc);
    f32x4 z4 = *(const f32x4*)(zb + 4 * 2176) + *(const f32x4*)(bf2 + gc);
    f32x4 z5 = *(const f32x4*)(zb + 5 * 2176) + *(const f32x4*)(bi2 + gc);
    f32x4 z6 = *(const f32x4*)(zb + 6 * 2176) + *(const f32x4*)(bc2 + gc);
    f32x4 z7 = *(const f32x4*)(zb + 7 * 2176) + *(const f32x4*)(bo2 + gc);
    f32x4 cl4 = *(const f32x4*)(c_light + (size_t)grow * H_DIM + gc);
    f32x4 hv, cv;
#pragma unroll
    for (int j = 0; j < 4; ++j) {
      float f1 = sigf(z0[j]);
      float i1 = sigf(z1[j]);
      float ch1 = tanhfast(z2[j]);
      float o1 = sigf(z3[j]);
      float f2 = sigf(z4[j]);
      float i2 = sigf(z5[j]);
      float ch2 = tanhfast(z6[j]);
      float o2 = sigf(z7[j]);
      float cn = f1 * cl4[j] + i1 * ch1 + f2 * cl4[j] + i2 * ch2;
      hv[j] = (o1 + o2) * tanhfast(cn);
      cv[j] = cn;
    }
    *(f32x4*)(out + (size_t)grow * H_DIM + gc) = hv;
    *(f32x4*)(out + (size_t)(B_DIM * H_DIM) + (size_t)grow * H_DIM + gc) = cv;
  }
}

extern "C" void kernel_launch(void* const* d_in, const int* in_sizes, int n_in,
                              void* d_out, int out_size, void* d_ws, size_t ws_size,
                              hipStream_t stream) {
  (void)in_sizes; (void)n_in; (void)out_size; (void)ws_size;
  const float* y       = (const float*)d_in[0];
  const float* h_light = (const float*)d_in[1];
  const float* c_light = (const float*)d_in[2];
  const float* h_temp  = (const float*)d_in[3];
  // d_in[4] = c_temp: dead in the reference computation.
  uint16_t* ws = (uint16_t*)d_ws;  // needs 50,331,648 B

  convert_kernel<<<16384, 192, 0, stream>>>(
      y, h_light, h_temp,
      (const float*)d_in[5],  (const float*)d_in[7],  (const float*)d_in[9],  (const float*)d_in[11],
      (const float*)d_in[13], (const float*)d_in[15], (const float*)d_in[17], (const float*)d_in[19],
      ws);

  lstm_fused_kernel<<<512, 512, 0, stream>>>(
      ws, c_light,
      (const float*)d_in[6],  (const float*)d_in[8],  (const float*)d_in[10], (const float*)d_in[12],
      (const float*)d_in[14], (const float*)d_in[16], (const float*)d_in[18], (const float*)d_in[20],
      (float*)d_out);
}